// Round 8
// baseline (46.295 us; speedup 1.0000x reference)
//
#include <hip/hip_runtime.h>
#include <math.h>

// ChamferLoss: pc_src [B,3,M] f32, pc_dst [B,3,N] f32 -> scalar mean over (B,M)
// of min_n ||src_m - dst_n||.
//
// Identity: min_n d2 = |a|^2 + min_n (|b|^2 - 2 a.b).
// dst4 = (-2bx,-2by,-2bz,|b|^2) precomputed to global; minseg reads it with
// BLOCK-UNIFORM addresses -> scalar s_load path (K$), freeing the DS pipe
// that was co-critical in R3/R7 (32 ds_read_b128 ~ 384cy vs 448cy VALU per
// CU round). Inner loop: 3 FMA + half v_min3 per pair, SGPR operands.
//
// R7 -> R8: LDS removed from minseg (no ds_read, no syncthreads); prep
// kernel builds dst4 + inits minenc (no memset dispatch). SPT=8,
// bounds(256,4), NSEG=64, 1024 blocks. Fused finish (ticket + fixed-point)
// unchanged.

#define TPB 256

constexpr int NB = 4;
constexpr int NM = 8192;
constexpr int NN = 8192;
constexpr int NSEG = 64;                          // dst segments
constexpr int SEG = NN / NSEG;                    // 128 dst per segment
constexpr int SPT = 8;                            // src points per thread
constexpr int SRC_PER_BLOCK = TPB * SPT;          // 2048
constexpr int NPTS = NB * NM;                     // 32768
constexpr int CHUNKS = NPTS / SRC_PER_BLOCK;      // 16
constexpr int CHUNKS_PER_B = NM / SRC_PER_BLOCK;  // 4
constexpr int NBLK_C = NPTS / TPB;                // 128

// Order-preserving float<->uint encode so unsigned atomicMin == float min.
__device__ __forceinline__ unsigned enc_f32(float f) {
    unsigned u = __float_as_uint(f);
    return (u & 0x80000000u) ? ~u : (u | 0x80000000u);
}
__device__ __forceinline__ float dec_f32(unsigned u) {
    unsigned b = (u & 0x80000000u) ? (u ^ 0x80000000u) : ~u;
    return __uint_as_float(b);
}

// Kernel 0: build dst4, init minenc and the sum/ticket cells.
__global__ __launch_bounds__(TPB) void prep_kernel(const float* __restrict__ dst,
                                                   float4* __restrict__ dst4,
                                                   unsigned* __restrict__ minenc,
                                                   unsigned long long* __restrict__ sumfix,
                                                   unsigned* __restrict__ ticket) {
    int idx = blockIdx.x * TPB + threadIdx.x;
    if (idx == 0) { *sumfix = 0ULL; *ticket = 0u; }
    int b = idx / NN, n = idx % NN;
    const float* p = dst + (size_t)b * 3 * NN;
    float x = p[n], y = p[NN + n], z = p[2 * NN + n];
    dst4[idx] = make_float4(-2.0f * x, -2.0f * y, -2.0f * z,
                            fmaf(x, x, fmaf(y, y, z * z)));
    if (idx < NPTS) minenc[idx] = 0xFFFFFFFFu;    // encodes > +inf
}

// Kernel 1: per (src-chunk, dst-segment) block; dst4 read block-uniform
// (scalar-load path), running min over 8 src points/thread, atomicMin out.
__global__ __launch_bounds__(TPB, 4) void minseg_kernel(const float* __restrict__ src,
                                                        const float4* __restrict__ dst4,
                                                        unsigned* __restrict__ minenc) {
    int chunk = blockIdx.x % CHUNKS;
    int seg   = blockIdx.x / CHUNKS;
    int b  = chunk / CHUNKS_PER_B;
    int t  = threadIdx.x;

    int m0 = (chunk % CHUNKS_PER_B) * SRC_PER_BLOCK + t;
    const float* sp = src + (size_t)b * 3 * NM;

    float ax[SPT], ay[SPT], az[SPT], mn[SPT];
#pragma unroll
    for (int k = 0; k < SPT; ++k) {
        int m = m0 + k * TPB;
        ax[k] = sp[m];
        ay[k] = sp[NM + m];
        az[k] = sp[2 * NM + m];
        mn[k] = 3.4e38f;
    }

    const float4* dp = dst4 + b * NN + seg * SEG;   // block-uniform base
    for (int j = 0; j < SEG; j += 4) {
        float4 d0 = dp[j];                          // uniform idx -> s_load
        float4 d1 = dp[j + 1];
        float4 d2 = dp[j + 2];
        float4 d3 = dp[j + 3];
#pragma unroll
        for (int k = 0; k < SPT; ++k) {
            float t0 = fmaf(az[k], d0.z, d0.w);
            t0 = fmaf(ay[k], d0.y, t0);
            t0 = fmaf(ax[k], d0.x, t0);
            float t1 = fmaf(az[k], d1.z, d1.w);
            t1 = fmaf(ay[k], d1.y, t1);
            t1 = fmaf(ax[k], d1.x, t1);
            float t2 = fmaf(az[k], d2.z, d2.w);
            t2 = fmaf(ay[k], d2.y, t2);
            t2 = fmaf(ax[k], d2.x, t2);
            float t3 = fmaf(az[k], d3.z, d3.w);
            t3 = fmaf(ay[k], d3.y, t3);
            t3 = fmaf(ax[k], d3.x, t3);
            float u = fminf(fminf(t2, t3), mn[k]);  // -> v_min3_f32
            mn[k] = fminf(fminf(t0, t1), u);        // -> v_min3_f32
        }
    }

#pragma unroll
    for (int k = 0; k < SPT; ++k) {
        int gm = b * NM + m0 + k * TPB;
        atomicMin(&minenc[gm], enc_f32(mn[k]));     // exact, order-independent
    }
}

// Kernel 2: per src point, d = sqrt(max(a^2 + minval, 0)); block tree-sum;
// deterministic fixed-point accumulate; last block (ticket) writes scalar.
__global__ __launch_bounds__(TPB) void finish_kernel(const float* __restrict__ src,
                                                     const unsigned* __restrict__ minenc,
                                                     unsigned long long* __restrict__ sumfix,
                                                     unsigned* __restrict__ ticket,
                                                     float* __restrict__ out) {
    int gm = blockIdx.x * TPB + threadIdx.x;
    int b = gm / NM, m = gm % NM;
    const float* sp = src + (size_t)b * 3 * NM;
    float x = sp[m], y = sp[NM + m], z = sp[2 * NM + m];
    float a2 = fmaf(x, x, fmaf(y, y, z * z));
    float v = dec_f32(minenc[gm]);
    float d = sqrtf(fmaxf(a2 + v, 0.0f));

    for (int off = 32; off > 0; off >>= 1) d += __shfl_down(d, off);
    __shared__ float wsum[4];
    int lane = threadIdx.x & 63, w = threadIdx.x >> 6;
    if (lane == 0) wsum[w] = d;
    __syncthreads();

    if (threadIdx.x == 0) {
        float bs = (wsum[0] + wsum[1]) + (wsum[2] + wsum[3]);
        // Fixed-point (32.32) accumulate: integer adds are associative ->
        // deterministic regardless of block order.
        unsigned long long inc = (unsigned long long)((double)bs * 4294967296.0);
        atomicAdd(sumfix, inc);
        __threadfence();                          // sum-add before ticket-add
        unsigned tk = atomicAdd(ticket, 1u);
        if (tk == NBLK_C - 1) {
            unsigned long long tot = atomicAdd(sumfix, 0ULL);  // coherent read
            out[0] = (float)((double)tot * (1.0 / 4294967296.0) * (1.0 / NPTS));
        }
    }
}

extern "C" void kernel_launch(void* const* d_in, const int* in_sizes, int n_in,
                              void* d_out, int out_size, void* d_ws, size_t ws_size,
                              hipStream_t stream) {
    const float* src = (const float*)d_in[0];   // [B,3,M]
    const float* dst = (const float*)d_in[1];   // [B,3,N]
    float* out = (float*)d_out;

    char* ws = (char*)d_ws;
    float4*   dst4   = (float4*)ws;                                  // 512 KB
    unsigned* minenc = (unsigned*)(ws + (size_t)NB * NN * 16);       // 128 KB
    unsigned long long* sumfix =
        (unsigned long long*)(ws + (size_t)NB * NN * 16 + (size_t)NPTS * 4);
    unsigned* ticket = (unsigned*)((char*)sumfix + 8);

    prep_kernel<<<(NB * NN) / TPB, TPB, 0, stream>>>(dst, dst4, minenc, sumfix, ticket);
    minseg_kernel<<<CHUNKS * NSEG, TPB, 0, stream>>>(src, dst4, minenc);
    finish_kernel<<<NBLK_C, TPB, 0, stream>>>(src, minenc, sumfix, ticket, out);
}